// Round 7
// baseline (136.394 us; speedup 1.0000x reference)
//
#include <hip/hip_runtime.h>

#define BLOCK 8
#define NGRID 512
#define NROWS_PAD 224   // dedup'd rows (~222) padded to a multiple of 4

// ---------------------------------------------------------------------------
// Compile-time replication of
//   np.random.RandomState(0).choice(np.array([1.0,3.0],f32), size=(512,8))
// (MT19937 legacy scalar seeding, one 32-bit draw per value, value = draw&1).
// Bit i of pattern byte = element i: g[i] = bit ? 3.0f : 1.0f.
// Rows dedup'd in first-occurrence order (argmax-neutral under strict-> scan).
// Scan order = dedup order (k-ascending); strict > keeps the FIRST max ==
// numpy argmax semantics exactly. No tie machinery needed at all.
// SCORE PIPELINE BIT-FROZEN (R0/R2/R4/R5, absmax 0.0078125): ascending-k fma
// chain, lone f32 square, Markstein CR division (residual==0 for pow2 norms,
// so one uniform code path is bit-exact for every norm).
// Padding rows = copy of row 0: identical score, never strictly greater,
// never selected.
// ---------------------------------------------------------------------------
struct RowTab {
  struct Row {
    float q[8];        // codeword as floats {1,3}
    float nf;          // norm = 8*(1+popcount)
    float rcf;         // RN(1/nf) (compile-time)
    unsigned int pat;  // pattern byte (epilogue)
    unsigned int pad;  // align to 48 B
  } r[NROWS_PAD];
  int nd;
};

constexpr int popcount8c(unsigned v) {
  int p = 0;
  for (int i = 0; i < 8; ++i) p += (v >> i) & 1u;
  return p;
}

constexpr RowTab make_rowtab() {
  RowTab t{};
  bool exists[256] = {};
  unsigned char pats[256] = {};
  // --- MT19937, numpy legacy scalar seed 0 ---
  unsigned mt[624] = {};
  {
    unsigned s = 0u;
    for (int i = 0; i < 624; ++i) {
      mt[i] = s;
      s = 1812433253u * (s ^ (s >> 30)) + (unsigned)(i + 1);
    }
  }
  int pos = 624;
  int nd = 0;
  for (int j = 0; j < NGRID; ++j) {
    unsigned char b = 0;
    for (int i = 0; i < BLOCK; ++i) {
      if (pos == 624) {
        for (int k = 0; k < 624; ++k) {
          int k1 = (k + 1 < 624) ? k + 1 : 0;
          int k397 = (k + 397 < 624) ? k + 397 : k + 397 - 624;
          unsigned y = (mt[k] & 0x80000000u) | (mt[k1] & 0x7fffffffu);
          unsigned v = mt[k397] ^ (y >> 1);
          if (y & 1u) v ^= 0x9908b0dfu;
          mt[k] = v;
        }
        pos = 0;
      }
      unsigned y = mt[pos++];
      y ^= y >> 11;
      y ^= (y << 7) & 0x9d2c5680u;
      y ^= (y << 15) & 0xefc60000u;
      y ^= y >> 18;
      if (y & 1u) b |= (unsigned char)(1u << i);
    }
    if (!exists[b]) {
      exists[b] = true;
      pats[nd++] = b;
    }
  }
  t.nd = nd;
  for (int j = 0; j < NROWS_PAD; ++j) {
    unsigned b = pats[(j < nd) ? j : 0];     // padding = row 0 clone (never wins)
    for (int i = 0; i < 8; ++i) t.r[j].q[i] = ((b >> i) & 1u) ? 3.0f : 1.0f;
    int pc = popcount8c(b);
    float nf = (float)(8 * (1 + pc));
    t.r[j].nf = nf;
    t.r[j].rcf = 1.0f / nf;                  // RN reciprocal at compile time
    t.r[j].pat = b;
    t.r[j].pad = 0u;
  }
  return t;
}

constexpr RowTab RT = make_rowtab();
static_assert(RT.nd > 0 && RT.nd <= NROWS_PAD, "sanity");

__constant__ RowTab g_rt = RT;   // wave-uniform access -> s_load stream, K$-hot

__global__ __launch_bounds__(256, 8) void _IQ2XSQuantWeight_12945031430379_kernel(
    const float* __restrict__ w, float* __restrict__ out, int nb) {
  int t = blockIdx.x * blockDim.x + threadIdx.x;
  if (t >= nb) return;

  const float4* wp = reinterpret_cast<const float4*>(w) + (size_t)2 * t;
  float4 w0 = wp[0];
  float4 w1 = wp[1];
  float wv[BLOCK] = {w0.x, w0.y, w0.z, w0.w, w1.x, w1.y, w1.z, w1.w};

  float a[BLOCK];
  unsigned sb = 0u;   // packed sign bits of w
#pragma unroll
  for (int i = 0; i < BLOCK; ++i) {
    a[i] = __builtin_fabsf(wv[i]);
    sb |= (__float_as_uint(wv[i]) >> 31) << i;
  }

  float gb = -1.0f;       // scores are >= 0
  unsigned gpat = 0u;

  // Compact hot loop: ~60 insts, I-cache resident; row data via scalar loads.
#pragma unroll 4
  for (int j = 0; j < NROWS_PAD; ++j) {
    const RowTab::Row& R = g_rt.r[j];
    // dot: ascending-index fma chain (bit-frozen reference order)
    float d = 0.0f;
#pragma unroll
    for (int i = 0; i < BLOCK; ++i) d = __builtin_fmaf(a[i], R.q[i], d);
    float dd = d * d;
    // Markstein CR division: == fl32(dd/nf) for all norms (residual==0 when
    // nf is a power of two, reducing to the exact dd*rcf).
    float q0 = dd * R.rcf;
    float rr = __builtin_fmaf(-R.nf, q0, dd);
    float sc = __builtin_fmaf(rr, R.rcf, q0);
    // strict >, k-ascending scan: first max == numpy argmax (exact ties)
    bool g = sc > gb;
    gb = g ? sc : gb;
    gpat = g ? R.pat : gpat;
  }

  // ---- epilogue: bit-identical to R5's (passed at absmax 0.0078125) ----
  unsigned bits = gpat;

  float p[BLOCK];
#pragma unroll
  for (int i = 0; i < BLOCK; ++i) {
    float a3 = a[i] * 3.0f;
    p[i] = ((bits >> i) & 1u) ? a3 : a[i];
  }
  float num = ((p[0] + p[1]) + (p[2] + p[3])) + ((p[4] + p[5]) + (p[6] + p[7]));

  int popc = __popc(bits);
  float normf = (float)(8 + (popc << 3));
  float scale = num / normf;                  // IEEE CR f32 divide (once)
  float s3 = scale * 3.0f;

  float o[BLOCK];
#pragma unroll
  for (int i = 0; i < BLOCK; ++i) {
    float mag = ((bits >> i) & 1u) ? s3 : scale;
    // copysign(mag, w) via sign-bit OR; exact-zero w -> 0 (a[i]==0)
    unsigned ob = __float_as_uint(mag) | (((sb >> i) & 1u) << 31);
    float v = __uint_as_float(ob);
    o[i] = (a[i] == 0.0f) ? 0.0f : v;
  }

  float4 o0 = {o[0], o[1], o[2], o[3]};
  float4 o1 = {o[4], o[5], o[6], o[7]};
  float4* op = reinterpret_cast<float4*>(out) + (size_t)2 * t;
  op[0] = o0;
  op[1] = o1;
}

extern "C" void kernel_launch(void* const* d_in, const int* in_sizes, int n_in,
                              void* d_out, int out_size, void* d_ws, size_t ws_size,
                              hipStream_t stream) {
  (void)n_in; (void)d_ws; (void)ws_size; (void)out_size;
  const float* w = (const float*)d_in[0];
  float* out = (float*)d_out;
  int n = in_sizes[0];
  int nb = n / BLOCK;
  int threads = 256;
  int blocks = (nb + threads - 1) / threads;
  _IQ2XSQuantWeight_12945031430379_kernel<<<blocks, threads, 0, stream>>>(w, out, nb);
}